// Round 10
// baseline (642.101 us; speedup 1.0000x reference)
//
#include <hip/hip_runtime.h>
#include <hip/hip_fp16.h>
#include <hip/hip_cooperative_groups.h>

namespace cg = cooperative_groups;

#define TPB 256
#define CAP 16384          // slack entries per 256-node bucket (padded fill ~5100)
#define CAPSH 14           // log2(CAP)

typedef __attribute__((ext_vector_type(8))) float f32x8;
typedef __attribute__((ext_vector_type(8))) unsigned short u16x8;
typedef __attribute__((ext_vector_type(4))) unsigned int u32x4;
typedef __attribute__((ext_vector_type(2))) _Float16 h16x2;

// Identity used: dis⊙(x@W) = (dis⊙x)@W and Agg(z@W) = (Agg z)@W, so each
// layer is gather(z) -> mm -> relu, with z = fp16(dis ⊙ activation).
// Buckets: 256 nodes each (dst>>8); bucket b owns pairs/csr[b*CAP..).
// CSR runs padded to a multiple of 8 with index N (zero row).
// meta[v] = { (offset<<8) | nbatches, bitcast(dis) }.
// Session ledger: R2 direct CSR = write-allocate blowup. R3/R4/R6/R9
// intra-kernel micro-theories all neutral; R5 spill regression; R8 MFMA mm
// neutral-negative; R7 pipelined gather + fdot2 = best standalone (185.0us).
// Layer time is invariant under every intra-kernel change -> the remaining
// unexplained signal is INTER-KERNEL: R1 added exactly one launch (net work
// unchanged) and cost +10us (4x noise) => per-dispatch front+drain ~5-10us,
// x7 dispatches ~25-30us of the budget.
// This round: ONE cooperative kernel (doc-blessed hipLaunchCooperativeKernel),
// grid sized to co-residency via occupancy API; phases {zero, scatter, fill+z0,
// L0, L1, Lfinal} separated by grid.sync(); per-wave dynamic tickets in layer
// phases (atomicAdd per 8-node tile) for tail balance. Gather/mm code is
// byte-identical to R7 -> absmax must stay 0.0004882812.

__device__ __forceinline__ int ld_idx(const void* p, long long i, int is64) {
    return is64 ? (int)((const long long*)p)[i] : ((const int*)p)[i];
}

__device__ __forceinline__ ushort4 f4_to_h4(float4 v) {
    ushort4 r;
    r.x = __half_as_ushort(__float2half_rn(v.x));
    r.y = __half_as_ushort(__float2half_rn(v.y));
    r.z = __half_as_ushort(__float2half_rn(v.z));
    r.w = __half_as_ushort(__float2half_rn(v.w));
    return r;
}

#if __has_builtin(__builtin_amdgcn_fdot2) && __has_builtin(__builtin_amdgcn_perm)
#define GCN_DOT2 1
#else
#define GCN_DOT2 0
#endif

// Accumulate the 8 features of TWO fp16 rows into f32 acc (R7-identical).
__device__ __forceinline__ void accum_row_pair(const u16x8& ra, const u16x8& rb,
                                               f32x8& acc) {
#if GCN_DOT2
    u32x4 a = __builtin_bit_cast(u32x4, ra);
    u32x4 b = __builtin_bit_cast(u32x4, rb);
    const h16x2 one = {(_Float16)1.0f, (_Float16)1.0f};
    #pragma unroll
    for (int j = 0; j < 4; ++j) {
        unsigned p0 = __builtin_amdgcn_perm(a[j], b[j], 0x05040100u); // h0 pair
        unsigned p1 = __builtin_amdgcn_perm(a[j], b[j], 0x07060302u); // h1 pair
        acc[2 * j]     = __builtin_amdgcn_fdot2(__builtin_bit_cast(h16x2, p0),
                                                one, acc[2 * j], false);
        acc[2 * j + 1] = __builtin_amdgcn_fdot2(__builtin_bit_cast(h16x2, p1),
                                                one, acc[2 * j + 1], false);
    }
#else
    #pragma unroll
    for (int i = 0; i < 8; ++i)
        acc[i] += __half2float(__ushort_as_half(ra[i])) +
                  __half2float(__ushort_as_half(rb[i]));
#endif
}

__device__ __forceinline__ void accum_batch(const u16x8 (&R)[8], f32x8& acc) {
    #pragma unroll
    for (int k = 0; k < 8; k += 2) accum_row_pair(R[k], R[k + 1], acc);
}

__device__ __forceinline__ void load_batch(const u16x8* __restrict__ z8,
                                           u16x8 (&R)[8], int idx, int c,
                                           int base) {
    #pragma unroll
    for (int k = 0; k < 8; ++k) {
        int s = __shfl(idx, base + k);
        R[k] = z8[(size_t)s * 8 + c];
    }
}

// Pipelined cooperative gather (PADDED csr): ping-pong row buffers A/B
// (R7-identical; per-node summation order unchanged).
__device__ __forceinline__ f32x8 gather_rows(const u16x8* __restrict__ z8,
                                             const int* __restrict__ csr,
                                             int start, int nbatch, int c,
                                             f32x8 acc) {
    const int base = threadIdx.x & 56;           // 8-lane group base in wave
    if (nbatch <= 0) return acc;
    u16x8 A[8], B[8];
    int idx0 = csr[start + c];
    int idx_n = (nbatch > 1) ? csr[start + 8 + c] : 0;   // batch 1 idx
    load_batch(z8, A, idx0, c, base);
    int bt = 0;
    for (;;) {
        int idx_f = (bt + 2 < nbatch) ? csr[start + (bt + 2) * 8 + c] : 0;
        if (bt + 1 < nbatch) load_batch(z8, B, idx_n, c, base);
        accum_batch(A, acc);
        if (++bt >= nbatch) break;
        int idx_f2 = (bt + 2 < nbatch) ? csr[start + (bt + 2) * 8 + c] : 0;
        if (bt + 1 < nbatch) load_batch(z8, A, idx_f, c, base);
        accum_batch(B, acc);
        if (++bt >= nbatch) break;
        idx_n = idx_f2;
    }
    return acc;
}

// Shfl-based mm for 8-lane groups (R7-identical).
__device__ __forceinline__ f32x8 shfl_mm8(f32x8 s, const float4* Ws4, int c) {
    const int base = threadIdx.x & 56;
    f32x8 u = {0.f, 0.f, 0.f, 0.f, 0.f, 0.f, 0.f, 0.f};
    #pragma unroll
    for (int q = 0; q < 8; ++q) {
        #pragma unroll
        for (int r = 0; r < 8; ++r) {
            float hv = __shfl(s[r], base + q);   // feature q*8+r
            float4 w0 = Ws4[(q * 8 + r) * 16 + 2 * c];
            float4 w1 = Ws4[(q * 8 + r) * 16 + 2 * c + 1];
            u[0] = fmaf(hv, w0.x, u[0]);
            u[1] = fmaf(hv, w0.y, u[1]);
            u[2] = fmaf(hv, w0.z, u[2]);
            u[3] = fmaf(hv, w0.w, u[3]);
            u[4] = fmaf(hv, w1.x, u[4]);
            u[5] = fmaf(hv, w1.y, u[5]);
            u[6] = fmaf(hv, w1.z, u[6]);
            u[7] = fmaf(hv, w1.w, u[7]);
        }
    }
    return u;
}

__device__ __forceinline__ u16x8 f8_to_h8(f32x8 v) {
    u16x8 r;
    #pragma unroll
    for (int i = 0; i < 8; ++i)
        r[i] = __half_as_ushort(__float2half_rn(v[i]));
    return r;
}

// ---------------------------------------------------------------------------
// The whole pipeline as one cooperative kernel.
// ---------------------------------------------------------------------------
__global__ __launch_bounds__(TPB, 2) void fused_all(
    const void* __restrict__ ei, long long E,
    const float* __restrict__ x,
    int* __restrict__ gcur, int* __restrict__ tick,
    int* __restrict__ pairs, int2* __restrict__ meta, int* __restrict__ csr,
    u16x8* __restrict__ zbA, u16x8* __restrict__ zbB,
    const float* __restrict__ b0, const float* __restrict__ W0,
    const float* __restrict__ b1, const float* __restrict__ W1,
    const float* __restrict__ b2, const float* __restrict__ W2,
    const float* __restrict__ Wl, const float* __restrict__ bl,
    float* __restrict__ out, int N, int nbuck)
{
    cg::grid_group grid = cg::this_grid();
    __shared__ int sA[TPB];                      // histogram / cursor
    __shared__ int sB[TPB];                      // block cursors / scan
    __shared__ float sdis[TPB];
    __shared__ int s_is64;
    __shared__ float Ws[64 * 64];                // 16 KB weight stage
    __shared__ float Wls[64 * 8];
    __shared__ float bls[8];
    const int t = threadIdx.x;
    const int bid = blockIdx.x;
    const int nblk = gridDim.x;

    // ---- phase 0: zero global counters; per-block edge-dtype detect ----
    if (bid == 0) {
        if (t < 256) gcur[t] = 0;
        if (t < 8)   tick[t] = 0;
    }
    if (t < 64) {
        const unsigned int* w = (const unsigned int*)ei;
        unsigned long long m = __ballot(w[2 * t + 1] != 0u);
        if (t == 0) s_is64 = (m == 0ull) ? 1 : 0;
    }
    __threadfence();
    grid.sync();
    const int is64 = s_is64;

    // ---- phase 1: scatter (count -> reserve -> re-read+write) ----
    {
        long long chunk = (E + nblk - 1) / nblk;
        long long c0 = (long long)bid * chunk;
        long long c1 = (c0 + chunk < E) ? c0 + chunk : E;
        sA[t] = 0;
        __syncthreads();
        for (long long e = c0 + t; e < c1; e += TPB) {
            int d = ld_idx(ei, E + e, is64);
            atomicAdd(&sA[d >> 8], 1);
        }
        __syncthreads();
        if (sA[t]) sB[t] = (t << CAPSH) + atomicAdd(&gcur[t], sA[t]);
        __syncthreads();
        for (long long e = c0 + t; e < c1; e += TPB) {
            int sv = ld_idx(ei, e, is64);
            int d  = ld_idx(ei, E + e, is64);
            int pos = atomicAdd(&sB[d >> 8], 1);
            pairs[pos] = (sv << 8) | (d & 255);
        }
    }
    __threadfence();
    grid.sync();

    // ---- phase 2: per-bucket degree/scan/csr fill + z0 conversion ----
    for (int b = bid; b < nbuck; b += nblk) {
        int base = b << CAPSH;
        int ecnt = gcur[b];
        sA[t] = 0;
        __syncthreads();
        for (int e = base + t; e < base + ecnt; e += TPB)
            atomicAdd(&sA[pairs[e] & 255], 1);
        __syncthreads();
        int dvv = sA[t];
        int pv = (dvv + 7) & ~7;                 // padded to multiple of 8
        sB[t] = pv;
        __syncthreads();
        for (int off = 1; off < TPB; off <<= 1) {
            int u = 0;
            if (t >= off) u = sB[t - off];
            __syncthreads();
            sB[t] += u;
            __syncthreads();
        }
        int o = base + sB[t] - pv;               // absolute padded offset
        sA[t] = o;                               // becomes cursor
        float dd = rsqrtf((float)(dvv + 1));     // +1 self loop
        sdis[t] = dd;
        int node = (b << 8) + t;
        if (node < N)
            meta[node] = make_int2((o << 8) | (pv >> 3), __float_as_int(dd));
        __syncthreads();
        for (int e = base + t; e < base + ecnt; e += TPB) {
            int p = pairs[e];
            int pos = atomicAdd(&sA[p & 255], 1);
            csr[pos] = p >> 8;
        }
        for (int e = o + dvv; e < o + pv; ++e) csr[e] = N;  // pad, zero row

        int ni = t >> 4, cc = t & 15;            // z0 = fp16(dis*x)
        ushort4* z0 = (ushort4*)zbA;
        for (int p = 0; p < 16; ++p) {
            int nd = (b << 8) + p * 16 + ni;
            if (nd < N) {
                float dsc = sdis[p * 16 + ni];
                float4 h = ((const float4*)x)[(size_t)nd * 16 + cc];
                float4 r = {h.x * dsc, h.y * dsc, h.z * dsc, h.w * dsc};
                z0[(size_t)nd * 16 + cc] = f4_to_h4(r);
            }
        }
        __syncthreads();
    }
    if (bid == 0 && t < 16)
        ((ushort4*)zbA)[(size_t)N * 16 + t] = make_ushort4(0, 0, 0, 0);
    __threadfence();
    grid.sync();

    // ---- layer phases: dynamic per-wave tickets (8 nodes per ticket) ----
    const int lane = t & 63;
    const int g = lane >> 3, c = lane & 7;
    const int nwt = (N + 7) / 8;                 // 6250 wave-tiles

    #pragma unroll 1
    for (int layer = 0; layer < 2; ++layer) {
        const u16x8* z   = (layer == 0) ? zbA : zbB;
        u16x8* zout      = (layer == 0) ? zbB : zbA;
        const float* Wp  = (layer == 0) ? W0 : W1;
        const float* bp  = (layer == 0) ? b0 : b1;
        int* tk          = tick + layer;

        float4* Ws4 = (float4*)Ws;
        const float4* W4g = (const float4*)Wp;
        #pragma unroll
        for (int i = 0; i < 4; ++i) Ws4[t + i * TPB] = W4g[t + i * TPB];
        if (bid == 0 && t < 8) {                 // zero row N of this output
            u16x8 zz = {0, 0, 0, 0, 0, 0, 0, 0};
            zout[(size_t)N * 8 + t] = zz;
        }
        __syncthreads();                         // Ws staged; waves run free

        for (;;) {
            int wt0 = 0;
            if (lane == 0) wt0 = atomicAdd(tk, 1);
            int wt = __shfl(wt0, 0);
            if (wt >= nwt) break;
            int node = wt * 8 + g;
            f32x8 s = {0.f, 0.f, 0.f, 0.f, 0.f, 0.f, 0.f, 0.f};
            float dv = 0.f;
            if (node < N) {
                int2 m = meta[node];
                int start = ((unsigned)m.x) >> 8;
                int nbatch = m.x & 255;
                dv = __int_as_float(m.y);
                u16x8 v = z[(size_t)node * 8 + c];   // self-loop term z_v
                #pragma unroll
                for (int i = 0; i < 8; ++i)
                    s[i] = __half2float(__ushort_as_half(v[i]));
                s = gather_rows(z, csr, start, nbatch, c, s);
            }
            f32x8 u = shfl_mm8(s, Ws4, c);
            if (node < N) {
                float4 bb0 = ((const float4*)bp)[2 * c];
                float4 bb1 = ((const float4*)bp)[2 * c + 1];
                f32x8 r;
                r[0] = fmaxf(fmaf(dv, u[0], bb0.x), 0.f) * dv;
                r[1] = fmaxf(fmaf(dv, u[1], bb0.y), 0.f) * dv;
                r[2] = fmaxf(fmaf(dv, u[2], bb0.z), 0.f) * dv;
                r[3] = fmaxf(fmaf(dv, u[3], bb0.w), 0.f) * dv;
                r[4] = fmaxf(fmaf(dv, u[4], bb1.x), 0.f) * dv;
                r[5] = fmaxf(fmaf(dv, u[5], bb1.y), 0.f) * dv;
                r[6] = fmaxf(fmaf(dv, u[6], bb1.z), 0.f) * dv;
                r[7] = fmaxf(fmaf(dv, u[7], bb1.w), 0.f) * dv;
                zout[(size_t)node * 8 + c] = f8_to_h8(r);
            }
        }
        __threadfence();
        grid.sync();
    }

    // ---- final layer: gather(zbA) -> W2 mm -> relu -> 64->8 mm -> out ----
    {
        float4* Ws4 = (float4*)Ws;
        const float4* W4g = (const float4*)W2;
        #pragma unroll
        for (int i = 0; i < 4; ++i) Ws4[t + i * TPB] = W4g[t + i * TPB];
        if (t < 128) ((float4*)Wls)[t] = ((const float4*)Wl)[t];
        if (t < 8) bls[t] = bl[t];
        __syncthreads();

        for (;;) {
            int wt0 = 0;
            if (lane == 0) wt0 = atomicAdd(tick + 2, 1);
            int wt = __shfl(wt0, 0);
            if (wt >= nwt) break;
            int node = wt * 8 + g;
            f32x8 s = {0.f, 0.f, 0.f, 0.f, 0.f, 0.f, 0.f, 0.f};
            float dv = 0.f;
            if (node < N) {
                int2 m = meta[node];
                int start = ((unsigned)m.x) >> 8;
                int nbatch = m.x & 255;
                dv = __int_as_float(m.y);
                u16x8 v = zbA[(size_t)node * 8 + c];
                #pragma unroll
                for (int i = 0; i < 8; ++i)
                    s[i] = __half2float(__ushort_as_half(v[i]));
                s = gather_rows(zbA, csr, start, nbatch, c, s);
            }
            f32x8 u = shfl_mm8(s, Ws4, c);
            float4 bb0 = ((const float4*)b2)[2 * c];
            float4 bb1 = ((const float4*)b2)[2 * c + 1];
            f32x8 h;
            h[0] = fmaxf(fmaf(dv, u[0], bb0.x), 0.f);
            h[1] = fmaxf(fmaf(dv, u[1], bb0.y), 0.f);
            h[2] = fmaxf(fmaf(dv, u[2], bb0.z), 0.f);
            h[3] = fmaxf(fmaf(dv, u[3], bb0.w), 0.f);
            h[4] = fmaxf(fmaf(dv, u[4], bb1.x), 0.f);
            h[5] = fmaxf(fmaf(dv, u[5], bb1.y), 0.f);
            h[6] = fmaxf(fmaf(dv, u[6], bb1.z), 0.f);
            h[7] = fmaxf(fmaf(dv, u[7], bb1.w), 0.f);

            const int base = t & 56;
            float acc = bls[c];
            #pragma unroll
            for (int qq = 0; qq < 8; ++qq) {
                #pragma unroll
                for (int rr = 0; rr < 8; ++rr) {
                    float hv = __shfl(h[rr], base + qq);
                    acc = fmaf(hv, Wls[(qq * 8 + rr) * 8 + c], acc);
                }
            }
            if (node < N) out[(size_t)node * 8 + c] = acc;
        }
    }
}

extern "C" void kernel_launch(void* const* d_in, const int* in_sizes, int n_in,
                              void* d_out, int out_size, void* d_ws, size_t ws_size,
                              hipStream_t stream) {
    const float* x  = (const float*)d_in[0];
    const void*  ei = d_in[1];
    const float* W0 = (const float*)d_in[2];
    const float* b0 = (const float*)d_in[3];
    const float* W1 = (const float*)d_in[4];
    const float* b1 = (const float*)d_in[5];
    const float* W2 = (const float*)d_in[6];
    const float* b2 = (const float*)d_in[7];
    const float* Wl = (const float*)d_in[8];
    const float* bl = (const float*)d_in[9];

    long long E = in_sizes[1] / 2;                       // 800000
    const int dh = in_sizes[3];                          // 64
    const int din = in_sizes[2] / dh;                    // 64
    int N = in_sizes[0] / din;                           // 50000
    int nbuck = (N + 255) >> 8;                          // 196 buckets

    // Workspace carve (256-aligned): ~39 MB total
    char* ws = (char*)d_ws;
    size_t off = 0;
    auto alloc = [&](size_t bytes) -> char* {
        char* r = ws + off;
        off += (bytes + 255) & ~(size_t)255;
        return r;
    };
    int*   gcur  = (int*)  alloc(1024);
    int*   tick  = (int*)  alloc(256);
    int2*  meta  = (int2*) alloc((size_t)N * 8);
    int*   pairs = (int*)  alloc((size_t)nbuck * CAP * 4);     // 12.8 MB
    int*   csr   = (int*)  alloc((size_t)nbuck * CAP * 4);     // 12.8 MB
    u16x8* zbA   = (u16x8*)alloc((size_t)(N + 1) * 64 * 2);    // fp16 rows
    u16x8* zbB   = (u16x8*)alloc((size_t)(N + 1) * 64 * 2);
    float* outp  = (float*)d_out;

    // Co-resident grid sizing (cached; host-side queries are capture-safe).
    static int gridBlocks = 0;
    if (gridBlocks == 0) {
        int perCU = 0, nCU = 0, dev = 0;
        hipGetDevice(&dev);
        hipOccupancyMaxActiveBlocksPerMultiprocessor(&perCU, fused_all, TPB, 0);
        hipDeviceGetAttribute(&nCU, hipDeviceAttributeMultiprocessorCount, dev);
        if (perCU < 1) perCU = 1;
        if (nCU < 1) nCU = 256;
        gridBlocks = perCU * nCU;
        if (gridBlocks > 2048) gridBlocks = 2048;
    }

    void* args[] = {
        (void*)&ei, (void*)&E, (void*)&x,
        (void*)&gcur, (void*)&tick, (void*)&pairs, (void*)&meta, (void*)&csr,
        (void*)&zbA, (void*)&zbB,
        (void*)&b0, (void*)&W0, (void*)&b1, (void*)&W1, (void*)&b2, (void*)&W2,
        (void*)&Wl, (void*)&bl, (void*)&outp, (void*)&N, (void*)&nbuck
    };
    hipLaunchCooperativeKernel((void*)fused_all, dim3(gridBlocks), dim3(TPB),
                               args, 0, stream);
}

// Round 11
// 192.392 us; speedup vs baseline: 3.3375x; 3.3375x over previous
//
#include <hip/hip_runtime.h>
#include <hip/hip_fp16.h>

#define TPB 256
#define P4TPB 1024         // wide p4_fill block (16 waves)
#define CAP 16384          // slack entries per 256-node bucket (padded fill ~5100)
#define CAPSH 14           // log2(CAP)
#define SC_BLOCKS 1024     // scatter blocks (4/CU)

typedef __attribute__((ext_vector_type(8))) float f32x8;
typedef __attribute__((ext_vector_type(8))) unsigned short u16x8;
typedef __attribute__((ext_vector_type(4))) unsigned int u32x4;
typedef __attribute__((ext_vector_type(2))) _Float16 h16x2;

// Identity used: dis⊙(x@W) = (dis⊙x)@W and Agg(z@W) = (Agg z)@W, so each
// layer is gather(z) -> mm -> relu, with z = fp16(dis ⊙ activation).
// Buckets: 256 nodes each (dst>>8); bucket b owns pairs/csr[b*CAP..).
// CSR runs padded to a multiple of 8 with index N (zero row).
// meta[v] = { (offset<<8) | nbatches, bitcast(dis) }.
// Session ledger: R2 direct CSR = write-allocate blowup. R3/R4/R6/R9 layer
// micro-theories neutral; R5 spill regression; R8 MFMA neutral-negative;
// R10 cooperative fusion = 642us (grid.sync drains per-XCD L2 -> cold
// gathers; 103MB FETCH). R7 = best (185.0us). Layers are at a latency
// equilibrium; leave them alone. This round: widen the two preprocessing
// kernels only -- p3 at 1024 blocks (was 1/CU), p4 at 1024 threads (was
// 0.77 waves/SIMD chip-wide). Outputs bit-identical.

__device__ __forceinline__ int ld_idx(const void* p, long long i, int is64) {
    return is64 ? (int)((const long long*)p)[i] : ((const int*)p)[i];
}

__device__ __forceinline__ ushort4 f4_to_h4(float4 v) {
    ushort4 r;
    r.x = __half_as_ushort(__float2half_rn(v.x));
    r.y = __half_as_ushort(__float2half_rn(v.y));
    r.z = __half_as_ushort(__float2half_rn(v.z));
    r.w = __half_as_ushort(__float2half_rn(v.w));
    return r;
}

// ---------------------------------------------------------------------------
// Scatter: pass A histograms dst buckets (LDS), one global atomic per
// (block,bucket) reserves a contiguous chunk, pass B re-reads edges (L2/L3
// warm) and writes pairs into the chunk. gcur must be zeroed.
// ---------------------------------------------------------------------------
__global__ __launch_bounds__(TPB) void p3_scatter(const void* __restrict__ ei,
                                                  long long E,
                                                  int* __restrict__ gcur,
                                                  int* __restrict__ pairs) {
    __shared__ int cnt[256];
    __shared__ int cur2[256];
    __shared__ int s_is64;
    int t = threadIdx.x;
    if (t < 64) {
        const unsigned int* w = (const unsigned int*)ei;
        unsigned long long m = __ballot(w[2 * t + 1] != 0u);
        if (t == 0) s_is64 = (m == 0ull) ? 1 : 0;
    }
    cnt[t] = 0;
    __syncthreads();
    const int is64 = s_is64;
    long long chunk = (E + SC_BLOCKS - 1) / SC_BLOCKS;
    long long s0 = (long long)blockIdx.x * chunk;
    long long s1 = (s0 + chunk < E) ? s0 + chunk : E;

    for (long long e = s0 + t; e < s1; e += TPB) {       // pass A: count
        int d = ld_idx(ei, E + e, is64);
        atomicAdd(&cnt[d >> 8], 1);
    }
    __syncthreads();
    if (cnt[t]) cur2[t] = (t << CAPSH) + atomicAdd(&gcur[t], cnt[t]);
    __syncthreads();
    for (long long e = s0 + t; e < s1; e += TPB) {       // pass B: write
        int sv = ld_idx(ei, e, is64);
        int d  = ld_idx(ei, E + e, is64);
        int pos = atomicAdd(&cur2[d >> 8], 1);
        pairs[pos] = (sv << 8) | (d & 255);
    }
}

// ---------------------------------------------------------------------------
// One WIDE block (1024 thr) per bucket: degree count -> pad-to-8 scan (256
// lanes, all threads at the barriers) -> meta, csr scatter via LDS cursors +
// pad with index N, then z0 = fp16(dis*x). Same outputs as the 256-thread
// version, 4x the edge/z0 parallelism.
// ---------------------------------------------------------------------------
__global__ __launch_bounds__(P4TPB) void p4_fill(const int* __restrict__ pairs,
                                                 const int* __restrict__ gcur,
                                                 const float* __restrict__ x,
                                                 int2* __restrict__ meta,
                                                 int* __restrict__ csr,
                                                 ushort4* __restrict__ z0, int N) {
    __shared__ int ldeg[256];
    __shared__ int ssc[256];
    __shared__ int cur[256];
    __shared__ float fdis[256];
    int t = threadIdx.x;
    int b = blockIdx.x;
    int base = b << CAPSH;
    int ecnt = gcur[b];                          // real edges in this bucket
    if (t < 256) ldeg[t] = 0;
    __syncthreads();
    for (int e = base + t; e < base + ecnt; e += P4TPB)
        atomicAdd(&ldeg[pairs[e] & 255], 1);
    __syncthreads();
    int dv = (t < 256) ? ldeg[t] : 0;
    int pv = (dv + 7) & ~7;                      // padded to multiple of 8
    if (t < 256) ssc[t] = pv;
    __syncthreads();
    for (int off = 1; off < 256; off <<= 1) {
        int u = 0;
        if (t >= off && t < 256) u = ssc[t - off];
        __syncthreads();
        if (t < 256) ssc[t] += u;
        __syncthreads();
    }
    int o = 0;
    if (t < 256) {
        o = base + ssc[t] - pv;                  // absolute padded offset
        cur[t] = o;
        float dd = rsqrtf((float)(dv + 1));      // +1 self loop
        fdis[t] = dd;
        int node = (b << 8) + t;
        if (node < N)
            meta[node] = make_int2((o << 8) | (pv >> 3), __float_as_int(dd));
    }
    __syncthreads();
    for (int e = base + t; e < base + ecnt; e += P4TPB) {
        int p = pairs[e];
        int pos = atomicAdd(&cur[p & 255], 1);
        csr[pos] = p >> 8;
    }
    if (t < 256)
        for (int e = o + dv; e < o + pv; ++e) csr[e] = N;   // pad, zero row

    // z0 conversion: 4 passes, 64 nodes each, coalesced float4 reads.
    int ni = t >> 4, c = t & 15;                 // ni in 0..63
    for (int p = 0; p < 4; ++p) {
        int nd = (b << 8) + p * 64 + ni;
        if (nd < N) {
            float dvv = fdis[p * 64 + ni];
            float4 h = ((const float4*)x)[(size_t)nd * 16 + c];
            float4 r = {h.x * dvv, h.y * dvv, h.z * dvv, h.w * dvv};
            z0[(size_t)nd * 16 + c] = f4_to_h4(r);
        }
    }
    if (b == 0 && t < 16) z0[(size_t)N * 16 + t] = make_ushort4(0, 0, 0, 0);
}

// ---------------------------------------------------------------------------
// Gather building blocks (R7-identical)
// ---------------------------------------------------------------------------

#if __has_builtin(__builtin_amdgcn_fdot2) && __has_builtin(__builtin_amdgcn_perm)
#define GCN_DOT2 1
#else
#define GCN_DOT2 0
#endif

// Accumulate the 8 features of TWO fp16 rows into f32 acc.
__device__ __forceinline__ void accum_row_pair(const u16x8& ra, const u16x8& rb,
                                               f32x8& acc) {
#if GCN_DOT2
    u32x4 a = __builtin_bit_cast(u32x4, ra);
    u32x4 b = __builtin_bit_cast(u32x4, rb);
    const h16x2 one = {(_Float16)1.0f, (_Float16)1.0f};
    #pragma unroll
    for (int j = 0; j < 4; ++j) {
        unsigned p0 = __builtin_amdgcn_perm(a[j], b[j], 0x05040100u); // h0 pair
        unsigned p1 = __builtin_amdgcn_perm(a[j], b[j], 0x07060302u); // h1 pair
        acc[2 * j]     = __builtin_amdgcn_fdot2(__builtin_bit_cast(h16x2, p0),
                                                one, acc[2 * j], false);
        acc[2 * j + 1] = __builtin_amdgcn_fdot2(__builtin_bit_cast(h16x2, p1),
                                                one, acc[2 * j + 1], false);
    }
#else
    #pragma unroll
    for (int i = 0; i < 8; ++i)
        acc[i] += __half2float(__ushort_as_half(ra[i])) +
                  __half2float(__ushort_as_half(rb[i]));
#endif
}

__device__ __forceinline__ void accum_batch(const u16x8 (&R)[8], f32x8& acc) {
    #pragma unroll
    for (int k = 0; k < 8; k += 2) accum_row_pair(R[k], R[k + 1], acc);
}

__device__ __forceinline__ void load_batch(const u16x8* __restrict__ z8,
                                           u16x8 (&R)[8], int idx, int c,
                                           int base) {
    #pragma unroll
    for (int k = 0; k < 8; ++k) {
        int s = __shfl(idx, base + k);
        R[k] = z8[(size_t)s * 8 + c];
    }
}

// Pipelined cooperative gather (PADDED csr): ping-pong row buffers A/B.
__device__ __forceinline__ f32x8 gather_rows(const u16x8* __restrict__ z8,
                                             const int* __restrict__ csr,
                                             int start, int nbatch, int c,
                                             f32x8 acc) {
    const int base = threadIdx.x & 56;           // 8-lane group base in wave
    if (nbatch <= 0) return acc;
    u16x8 A[8], B[8];
    int idx0 = csr[start + c];
    int idx_n = (nbatch > 1) ? csr[start + 8 + c] : 0;   // batch 1 idx
    load_batch(z8, A, idx0, c, base);
    int bt = 0;
    for (;;) {
        int idx_f = (bt + 2 < nbatch) ? csr[start + (bt + 2) * 8 + c] : 0;
        if (bt + 1 < nbatch) load_batch(z8, B, idx_n, c, base);
        accum_batch(A, acc);
        if (++bt >= nbatch) break;
        int idx_f2 = (bt + 2 < nbatch) ? csr[start + (bt + 2) * 8 + c] : 0;
        if (bt + 1 < nbatch) load_batch(z8, A, idx_f, c, base);
        accum_batch(B, acc);
        if (++bt >= nbatch) break;
        idx_n = idx_f2;
    }
    return acc;
}

// Shfl-based mm for 8-lane groups (R7-identical).
__device__ __forceinline__ f32x8 shfl_mm8(f32x8 s, const float4* Ws4, int c) {
    const int base = threadIdx.x & 56;
    f32x8 u = {0.f, 0.f, 0.f, 0.f, 0.f, 0.f, 0.f, 0.f};
    #pragma unroll
    for (int q = 0; q < 8; ++q) {
        #pragma unroll
        for (int r = 0; r < 8; ++r) {
            float hv = __shfl(s[r], base + q);   // feature q*8+r
            float4 w0 = Ws4[(q * 8 + r) * 16 + 2 * c];
            float4 w1 = Ws4[(q * 8 + r) * 16 + 2 * c + 1];
            u[0] = fmaf(hv, w0.x, u[0]);
            u[1] = fmaf(hv, w0.y, u[1]);
            u[2] = fmaf(hv, w0.z, u[2]);
            u[3] = fmaf(hv, w0.w, u[3]);
            u[4] = fmaf(hv, w1.x, u[4]);
            u[5] = fmaf(hv, w1.y, u[5]);
            u[6] = fmaf(hv, w1.z, u[6]);
            u[7] = fmaf(hv, w1.w, u[7]);
        }
    }
    return u;
}

__device__ __forceinline__ u16x8 f8_to_h8(f32x8 v) {
    u16x8 r;
    #pragma unroll
    for (int i = 0; i < 8; ++i)
        r[i] = __half_as_ushort(__float2half_rn(v[i]));
    return r;
}

// ---------------------------------------------------------------------------
// Layer: s = z_v + Agg z_u (gather); u = s @ W; zout = fp16(dis*relu(dis*u+b)).
// 32 nodes/block, 8 threads/node. Only W in LDS (16 KB). (R7-identical.)
// ---------------------------------------------------------------------------
__global__ __launch_bounds__(TPB) void layer_mm(const u16x8* __restrict__ z,
                                                const int* __restrict__ csr,
                                                const int2* __restrict__ meta,
                                                const float* __restrict__ b,
                                                const float* __restrict__ W,
                                                u16x8* __restrict__ zout, int n) {
    __shared__ float Ws[64 * 64];
    int t = threadIdx.x;
    float4* Ws4 = (float4*)Ws;
    const float4* W4g = (const float4*)W;
    #pragma unroll
    for (int i = 0; i < 4; ++i) Ws4[t + i * TPB] = W4g[t + i * TPB];

    if (blockIdx.x == 0 && t < 8) {              // zero row N for next layer
        u16x8 zz = {0, 0, 0, 0, 0, 0, 0, 0};
        zout[(size_t)n * 8 + t] = zz;
    }

    int wave = t >> 6, lane = t & 63;
    int g = lane >> 3, c = lane & 7;
    int node = blockIdx.x * 32 + wave * 8 + g;
    f32x8 s = {0.f, 0.f, 0.f, 0.f, 0.f, 0.f, 0.f, 0.f};
    float dv = 0.f;
    if (node < n) {
        int2 m = meta[node];
        int start = ((unsigned)m.x) >> 8;
        int nbatch = m.x & 255;
        dv = __int_as_float(m.y);
        u16x8 v = z[(size_t)node * 8 + c];       // self-loop term z_v
        #pragma unroll
        for (int i = 0; i < 8; ++i) s[i] = __half2float(__ushort_as_half(v[i]));
        s = gather_rows(z, csr, start, nbatch, c, s);
    }
    __syncthreads();                             // Ws fully staged
    f32x8 u = shfl_mm8(s, Ws4, c);
    if (node < n) {
        float4 b0 = ((const float4*)b)[2 * c];
        float4 b1 = ((const float4*)b)[2 * c + 1];
        f32x8 r;
        r[0] = fmaxf(fmaf(dv, u[0], b0.x), 0.f) * dv;
        r[1] = fmaxf(fmaf(dv, u[1], b0.y), 0.f) * dv;
        r[2] = fmaxf(fmaf(dv, u[2], b0.z), 0.f) * dv;
        r[3] = fmaxf(fmaf(dv, u[3], b0.w), 0.f) * dv;
        r[4] = fmaxf(fmaf(dv, u[4], b1.x), 0.f) * dv;
        r[5] = fmaxf(fmaf(dv, u[5], b1.y), 0.f) * dv;
        r[6] = fmaxf(fmaf(dv, u[6], b1.z), 0.f) * dv;
        r[7] = fmaxf(fmaf(dv, u[7], b1.w), 0.f) * dv;
        zout[(size_t)node * 8 + c] = f8_to_h8(r);    // z_{l+1}
    }
}

// ---------------------------------------------------------------------------
// Final: s = gather(z2); h = relu(dis*(s@W2)+b2); out = h @ linW + linb.
// Second mm: lane c computes output col c. (R7-identical.)
// ---------------------------------------------------------------------------
__global__ __launch_bounds__(TPB) void layer_final(const u16x8* __restrict__ z,
                                                   const int* __restrict__ csr,
                                                   const int2* __restrict__ meta,
                                                   const float* __restrict__ b,
                                                   const float* __restrict__ W,
                                                   const float* __restrict__ Wl,
                                                   const float* __restrict__ bl,
                                                   float* __restrict__ out, int n) {
    __shared__ float Ws[64 * 64];
    __shared__ float Wls[64 * 8];
    __shared__ float bls[8];
    int t = threadIdx.x;
    float4* Ws4 = (float4*)Ws;
    const float4* W4g = (const float4*)W;
    #pragma unroll
    for (int i = 0; i < 4; ++i) Ws4[t + i * TPB] = W4g[t + i * TPB];
    if (t < 128) ((float4*)Wls)[t] = ((const float4*)Wl)[t];
    if (t < 8) bls[t] = bl[t];

    int wave = t >> 6, lane = t & 63;
    int g = lane >> 3, c = lane & 7;
    int node = blockIdx.x * 32 + wave * 8 + g;
    f32x8 s = {0.f, 0.f, 0.f, 0.f, 0.f, 0.f, 0.f, 0.f};
    float dv = 0.f;
    if (node < n) {
        int2 m = meta[node];
        int start = ((unsigned)m.x) >> 8;
        int nbatch = m.x & 255;
        dv = __int_as_float(m.y);
        u16x8 v = z[(size_t)node * 8 + c];
        #pragma unroll
        for (int i = 0; i < 8; ++i) s[i] = __half2float(__ushort_as_half(v[i]));
        s = gather_rows(z, csr, start, nbatch, c, s);
    }
    __syncthreads();                             // Ws/Wls/bls staged
    f32x8 u = shfl_mm8(s, Ws4, c);
    float4 b0 = ((const float4*)b)[2 * c];
    float4 b1 = ((const float4*)b)[2 * c + 1];
    f32x8 h;
    h[0] = fmaxf(fmaf(dv, u[0], b0.x), 0.f);
    h[1] = fmaxf(fmaf(dv, u[1], b0.y), 0.f);
    h[2] = fmaxf(fmaf(dv, u[2], b0.z), 0.f);
    h[3] = fmaxf(fmaf(dv, u[3], b0.w), 0.f);
    h[4] = fmaxf(fmaf(dv, u[4], b1.x), 0.f);
    h[5] = fmaxf(fmaf(dv, u[5], b1.y), 0.f);
    h[6] = fmaxf(fmaf(dv, u[6], b1.z), 0.f);
    h[7] = fmaxf(fmaf(dv, u[7], b1.w), 0.f);

    // second mm (64 -> 8): lane c computes output col c.
    const int base = threadIdx.x & 56;
    float acc = bls[c];
    #pragma unroll
    for (int q = 0; q < 8; ++q) {
        #pragma unroll
        for (int r = 0; r < 8; ++r) {
            float hv = __shfl(h[r], base + q);   // feature q*8+r
            acc = fmaf(hv, Wls[(q * 8 + r) * 8 + c], acc);
        }
    }
    if (node < n) out[(size_t)node * 8 + c] = acc;
}

extern "C" void kernel_launch(void* const* d_in, const int* in_sizes, int n_in,
                              void* d_out, int out_size, void* d_ws, size_t ws_size,
                              hipStream_t stream) {
    const float* x  = (const float*)d_in[0];
    const void*  ei = d_in[1];
    const float* W0 = (const float*)d_in[2];
    const float* b0 = (const float*)d_in[3];
    const float* W1 = (const float*)d_in[4];
    const float* b1 = (const float*)d_in[5];
    const float* W2 = (const float*)d_in[6];
    const float* b2 = (const float*)d_in[7];
    const float* Wl = (const float*)d_in[8];
    const float* bl = (const float*)d_in[9];

    const long long E = in_sizes[1] / 2;                 // 800000
    const int dh = in_sizes[3];                          // 64
    const int din = in_sizes[2] / dh;                    // 64
    const int N = in_sizes[0] / din;                     // 50000
    const int nb = (N + 255) >> 8;                       // 196 buckets

    // Workspace carve (256-aligned): ~39 MB total
    char* ws = (char*)d_ws;
    size_t off = 0;
    auto alloc = [&](size_t bytes) -> char* {
        char* r = ws + off;
        off += (bytes + 255) & ~(size_t)255;
        return r;
    };
    int*   gcur    = (int*)  alloc(1024);
    int2*  meta    = (int2*) alloc((size_t)N * 8);
    int*   pairs   = (int*)  alloc((size_t)nb * CAP * 4);       // 12.8 MB
    int*   csr     = (int*)  alloc((size_t)nb * CAP * 4);       // 12.8 MB
    u16x8* zbA     = (u16x8*)alloc((size_t)(N + 1) * 64 * 2);   // fp16 rows (+zero row)
    u16x8* zbB     = (u16x8*)alloc((size_t)(N + 1) * 64 * 2);

    // --- preprocessing ---
    hipMemsetAsync(gcur, 0, 256 * sizeof(int), stream);
    p3_scatter<<<SC_BLOCKS, TPB, 0, stream>>>(ei, E, gcur, pairs);
    p4_fill<<<nb, P4TPB, 0, stream>>>(pairs, gcur, x, meta, csr,
                                      (ushort4*)zbA, N);

    // --- 3 layers: gather -> mm -> relu ---
    const int gL = (N + 31) / 32;                        // 1563
    layer_mm<<<gL, TPB, 0, stream>>>(zbA, csr, meta, b0, W0, zbB, N);
    layer_mm<<<gL, TPB, 0, stream>>>(zbB, csr, meta, b1, W1, zbA, N);
    layer_final<<<gL, TPB, 0, stream>>>(zbA, csr, meta, b2, W2, Wl, bl,
                                        (float*)d_out, N);
}

// Round 12
// 188.253 us; speedup vs baseline: 3.4108x; 1.0220x over previous
//
#include <hip/hip_runtime.h>
#include <hip/hip_fp16.h>

#define TPB 256
#define CAP 16384          // slack entries per 256-node bucket (padded fill ~5100)
#define CAPSH 14           // log2(CAP)
#define SC_BLOCKS 256      // scatter blocks: ~12-edge (48B) pairs chunks per
                           // (block,bucket) -- near line-sized. 1024 blocks
                           // fragments to ~12B chunks -> write-allocate tax (R11).

typedef __attribute__((ext_vector_type(8))) float f32x8;
typedef __attribute__((ext_vector_type(8))) unsigned short u16x8;
typedef __attribute__((ext_vector_type(4))) unsigned int u32x4;
typedef __attribute__((ext_vector_type(2))) _Float16 h16x2;

// Identity used: dis⊙(x@W) = (dis⊙x)@W and Agg(z@W) = (Agg z)@W, so each
// layer is gather(z) -> mm -> relu, with z = fp16(dis ⊙ activation).
// Buckets: 256 nodes each (dst>>8); bucket b owns pairs/csr[b*CAP..).
// CSR runs padded to a multiple of 8 with index N (zero row).
// meta[v] = { (offset<<8) | nbatches, bitcast(dis) }.
//
// SESSION LEDGER (12 experiments, this file = R7, best = 185.0us):
//  R1  split z0 kernel + p3@1024: +10us (dispatch cost + fragmented chunks)
//  R2  direct CSR build: +56us (51MB write-allocate on scattered 4B writes)
//  R3  p3 de-spill (count-then-reread): neutral (R0's 21ms p3 was replay artifact)
//  R4  degree-binned perm: neutral (divergence not the bottleneck)
//  R5  dual-node mm, full unroll: +245us (VGPR=256 scratch spill, 124MB/dispatch)
//  R6  dual-node spill-fixed: +14us (outstanding rows/CU invariant: waves
//      halve x rows/wave double -> latency equilibrium unchanged)
//  R7  ping-pong pipelined gather + perm/fdot2 accumulate: -3.3us (BEST)
//  R8  MFMA mm (W in B-frags, 8 mfma/wave): +7.5us (mm was not the bound)
//  R9  barrier before gather (phase overlap): neutral (no lockstep effect)
//  R10 cooperative single-kernel fusion: +457us (grid.sync drains per-XCD
//      L2 -> cold gathers, 103MB FETCH, VALUBusy 3.6%)
//  R11 p3@1024 + 1024-thread p4: +7.4us (chunk fragmentation, see SC_BLOCKS)
//
// CONCLUSION: layers (~35us each) sit at a random-gather latency
// equilibrium -- ~850k random 128B row reads/layer from a 6.4MB working set
// that exceeds the 4MiB per-XCD L2, invariant under occupancy/ILP/engine/
// schedule changes. Remaining levers are barred: fp8-z halves the footprint
// to L2-fit but est. absmax ~0.05 (tolerance holds 4.9e-4); tile-synced
// gathers need a non-draining grid sync (R10 shows HW drains L2); scatter-
// side processing re-creates R2's write-allocate. Preprocessing (~28us:
// 2x edge read + CSR + z0) regressed under both widening attempts.
// This structure is at its practical roofline.

__device__ __forceinline__ int ld_idx(const void* p, long long i, int is64) {
    return is64 ? (int)((const long long*)p)[i] : ((const int*)p)[i];
}

__device__ __forceinline__ ushort4 f4_to_h4(float4 v) {
    ushort4 r;
    r.x = __half_as_ushort(__float2half_rn(v.x));
    r.y = __half_as_ushort(__float2half_rn(v.y));
    r.z = __half_as_ushort(__float2half_rn(v.z));
    r.w = __half_as_ushort(__float2half_rn(v.w));
    return r;
}

// ---------------------------------------------------------------------------
// Scatter: pass A histograms dst buckets (LDS), one global atomic per
// (block,bucket) reserves a contiguous chunk, pass B re-reads edges (L2/L3
// warm) and writes pairs into the chunk. gcur must be zeroed.
// ---------------------------------------------------------------------------
__global__ __launch_bounds__(TPB) void p3_scatter(const void* __restrict__ ei,
                                                  long long E,
                                                  int* __restrict__ gcur,
                                                  int* __restrict__ pairs) {
    __shared__ int cnt[TPB];
    __shared__ int cur2[TPB];
    __shared__ int s_is64;
    int t = threadIdx.x;
    if (t < 64) {
        const unsigned int* w = (const unsigned int*)ei;
        unsigned long long m = __ballot(w[2 * t + 1] != 0u);
        if (t == 0) s_is64 = (m == 0ull) ? 1 : 0;
    }
    cnt[t] = 0;
    __syncthreads();
    const int is64 = s_is64;
    long long chunk = (E + SC_BLOCKS - 1) / SC_BLOCKS;
    long long s0 = (long long)blockIdx.x * chunk;
    long long s1 = (s0 + chunk < E) ? s0 + chunk : E;

    for (long long e = s0 + t; e < s1; e += TPB) {       // pass A: count
        int d = ld_idx(ei, E + e, is64);
        atomicAdd(&cnt[d >> 8], 1);
    }
    __syncthreads();
    if (cnt[t]) cur2[t] = (t << CAPSH) + atomicAdd(&gcur[t], cnt[t]);
    __syncthreads();
    for (long long e = s0 + t; e < s1; e += TPB) {       // pass B: write
        int sv = ld_idx(ei, e, is64);
        int d  = ld_idx(ei, E + e, is64);
        int pos = atomicAdd(&cur2[d >> 8], 1);
        pairs[pos] = (sv << 8) | (d & 255);
    }
}

// ---------------------------------------------------------------------------
// One block per bucket: degree count (LDS atomics) -> pad-to-8 256-wide scan
// -> meta, csr scatter via LDS cursors + pad with index N, then
// z0 = fp16(dis * x) for this bucket's 256 nodes. Block 0 zeroes z0 row N.
// ---------------------------------------------------------------------------
__global__ __launch_bounds__(TPB) void p4_fill(const int* __restrict__ pairs,
                                               const int* __restrict__ gcur,
                                               const float* __restrict__ x,
                                               int2* __restrict__ meta,
                                               int* __restrict__ csr,
                                               ushort4* __restrict__ z0, int N) {
    __shared__ int ldeg[TPB];
    __shared__ int ssc[TPB];
    __shared__ int cur[TPB];
    __shared__ float fdis[TPB];
    int t = threadIdx.x;
    int b = blockIdx.x;
    int base = b << CAPSH;
    int ecnt = gcur[b];                          // real edges in this bucket
    ldeg[t] = 0;
    __syncthreads();
    for (int e = base + t; e < base + ecnt; e += TPB)
        atomicAdd(&ldeg[pairs[e] & 255], 1);
    __syncthreads();
    int dv = ldeg[t];
    int pv = (dv + 7) & ~7;                      // padded to multiple of 8
    ssc[t] = pv;
    __syncthreads();
    for (int off = 1; off < TPB; off <<= 1) {
        int u = 0;
        if (t >= off) u = ssc[t - off];
        __syncthreads();
        ssc[t] += u;
        __syncthreads();
    }
    int o = base + ssc[t] - pv;                  // absolute padded offset
    cur[t] = o;
    float dd = rsqrtf((float)(dv + 1));          // +1 self loop
    fdis[t] = dd;
    int node = (b << 8) + t;
    if (node < N)
        meta[node] = make_int2((o << 8) | (pv >> 3), __float_as_int(dd));
    __syncthreads();
    for (int e = base + t; e < base + ecnt; e += TPB) {
        int p = pairs[e];
        int pos = atomicAdd(&cur[p & 255], 1);
        csr[pos] = p >> 8;
    }
    for (int e = o + dv; e < o + pv; ++e) csr[e] = N;   // pad with zero row

    // z0 conversion: 16 passes, 16 nodes each, coalesced float4 reads.
    int ni = t >> 4, c = t & 15;
    for (int p = 0; p < 16; ++p) {
        int nd = (b << 8) + p * 16 + ni;
        if (nd < N) {
            float dvv = fdis[p * 16 + ni];
            float4 h = ((const float4*)x)[(size_t)nd * 16 + c];
            float4 r = {h.x * dvv, h.y * dvv, h.z * dvv, h.w * dvv};
            z0[(size_t)nd * 16 + c] = f4_to_h4(r);
        }
    }
    if (b == 0 && t < 16) z0[(size_t)N * 16 + t] = make_ushort4(0, 0, 0, 0);
}

// ---------------------------------------------------------------------------
// Gather building blocks
// ---------------------------------------------------------------------------

#if __has_builtin(__builtin_amdgcn_fdot2) && __has_builtin(__builtin_amdgcn_perm)
#define GCN_DOT2 1
#else
#define GCN_DOT2 0
#endif

// Accumulate the 8 features of TWO fp16 rows into f32 acc.
// perm packs (rowA.h_j, rowB.h_j) into one half2; fdot2 with (1,1) adds both
// halves into the f32 accumulator: 4 inst per 2 rows x 2 features (vs 8).
__device__ __forceinline__ void accum_row_pair(const u16x8& ra, const u16x8& rb,
                                               f32x8& acc) {
#if GCN_DOT2
    u32x4 a = __builtin_bit_cast(u32x4, ra);
    u32x4 b = __builtin_bit_cast(u32x4, rb);
    const h16x2 one = {(_Float16)1.0f, (_Float16)1.0f};
    #pragma unroll
    for (int j = 0; j < 4; ++j) {
        unsigned p0 = __builtin_amdgcn_perm(a[j], b[j], 0x05040100u); // h0 pair
        unsigned p1 = __builtin_amdgcn_perm(a[j], b[j], 0x07060302u); // h1 pair
        acc[2 * j]     = __builtin_amdgcn_fdot2(__builtin_bit_cast(h16x2, p0),
                                                one, acc[2 * j], false);
        acc[2 * j + 1] = __builtin_amdgcn_fdot2(__builtin_bit_cast(h16x2, p1),
                                                one, acc[2 * j + 1], false);
    }
#else
    #pragma unroll
    for (int i = 0; i < 8; ++i)
        acc[i] += __half2float(__ushort_as_half(ra[i])) +
                  __half2float(__ushort_as_half(rb[i]));
#endif
}

__device__ __forceinline__ void accum_batch(const u16x8 (&R)[8], f32x8& acc) {
    #pragma unroll
    for (int k = 0; k < 8; k += 2) accum_row_pair(R[k], R[k + 1], acc);
}

// Issue the 8 independent 16B row-chunk loads of one batch (indices via shfl
// from the 8-lane group's coalesced csr read). Fully unrolled: static regs.
__device__ __forceinline__ void load_batch(const u16x8* __restrict__ z8,
                                           u16x8 (&R)[8], int idx, int c,
                                           int base) {
    #pragma unroll
    for (int k = 0; k < 8; ++k) {
        int s = __shfl(idx, base + k);
        R[k] = z8[(size_t)s * 8 + c];
    }
}

// Pipelined cooperative gather (PADDED csr): ping-pong row buffers A/B.
// While batch bt accumulates (VALU), batch bt+1's 8 row loads are already in
// flight; csr indices are prefetched 2 batches ahead so the shfl never waits
// on a fresh csr load. Doubles per-wave outstanding rows at same occupancy.
__device__ __forceinline__ f32x8 gather_rows(const u16x8* __restrict__ z8,
                                             const int* __restrict__ csr,
                                             int start, int nbatch, int c,
                                             f32x8 acc) {
    const int base = threadIdx.x & 56;           // 8-lane group base in wave
    if (nbatch <= 0) return acc;
    u16x8 A[8], B[8];
    int idx0 = csr[start + c];
    int idx_n = (nbatch > 1) ? csr[start + 8 + c] : 0;   // batch 1 idx
    load_batch(z8, A, idx0, c, base);
    int bt = 0;
    for (;;) {
        // invariant: A = rows of batch bt, idx_n = csr idx of batch bt+1
        int idx_f = (bt + 2 < nbatch) ? csr[start + (bt + 2) * 8 + c] : 0;
        if (bt + 1 < nbatch) load_batch(z8, B, idx_n, c, base);
        accum_batch(A, acc);
        if (++bt >= nbatch) break;
        // B = rows of batch bt, idx_f = csr idx of batch bt+1
        int idx_f2 = (bt + 2 < nbatch) ? csr[start + (bt + 2) * 8 + c] : 0;
        if (bt + 1 < nbatch) load_batch(z8, A, idx_f, c, base);
        accum_batch(B, acc);
        if (++bt >= nbatch) break;
        idx_n = idx_f2;
    }
    return acc;
}

// Shfl-based mm for 8-lane groups: lane c holds features 8c..8c+7 of its
// node (f32x8); broadcast via __shfl; lane c accumulates output cols
// 8c..8c+7. Per-k Ws reads are 2 consecutive float4s (256 B/group contiguous,
// broadcast across groups -> conflict-free).
__device__ __forceinline__ f32x8 shfl_mm8(f32x8 s, const float4* Ws4, int c) {
    const int base = threadIdx.x & 56;
    f32x8 u = {0.f, 0.f, 0.f, 0.f, 0.f, 0.f, 0.f, 0.f};
    #pragma unroll
    for (int q = 0; q < 8; ++q) {
        #pragma unroll
        for (int r = 0; r < 8; ++r) {
            float hv = __shfl(s[r], base + q);   // feature q*8+r
            float4 w0 = Ws4[(q * 8 + r) * 16 + 2 * c];
            float4 w1 = Ws4[(q * 8 + r) * 16 + 2 * c + 1];
            u[0] = fmaf(hv, w0.x, u[0]);
            u[1] = fmaf(hv, w0.y, u[1]);
            u[2] = fmaf(hv, w0.z, u[2]);
            u[3] = fmaf(hv, w0.w, u[3]);
            u[4] = fmaf(hv, w1.x, u[4]);
            u[5] = fmaf(hv, w1.y, u[5]);
            u[6] = fmaf(hv, w1.z, u[6]);
            u[7] = fmaf(hv, w1.w, u[7]);
        }
    }
    return u;
}

__device__ __forceinline__ u16x8 f8_to_h8(f32x8 v) {
    u16x8 r;
    #pragma unroll
    for (int i = 0; i < 8; ++i)
        r[i] = __half_as_ushort(__float2half_rn(v[i]));
    return r;
}

// ---------------------------------------------------------------------------
// Layer: s = z_v + Agg z_u (gather); u = s @ W; zout = fp16(dis*relu(dis*u+b)).
// 32 nodes/block, 8 threads/node. Only W in LDS (16 KB).
// ---------------------------------------------------------------------------
__global__ __launch_bounds__(TPB) void layer_mm(const u16x8* __restrict__ z,
                                                const int* __restrict__ csr,
                                                const int2* __restrict__ meta,
                                                const float* __restrict__ b,
                                                const float* __restrict__ W,
                                                u16x8* __restrict__ zout, int n) {
    __shared__ float Ws[64 * 64];
    int t = threadIdx.x;
    float4* Ws4 = (float4*)Ws;
    const float4* W4g = (const float4*)W;
    #pragma unroll
    for (int i = 0; i < 4; ++i) Ws4[t + i * TPB] = W4g[t + i * TPB];

    if (blockIdx.x == 0 && t < 8) {              // zero row N for next layer
        u16x8 zz = {0, 0, 0, 0, 0, 0, 0, 0};
        zout[(size_t)n * 8 + t] = zz;
    }

    int wave = t >> 6, lane = t & 63;
    int g = lane >> 3, c = lane & 7;
    int node = blockIdx.x * 32 + wave * 8 + g;
    f32x8 s = {0.f, 0.f, 0.f, 0.f, 0.f, 0.f, 0.f, 0.f};
    float dv = 0.f;
    if (node < n) {
        int2 m = meta[node];
        int start = ((unsigned)m.x) >> 8;
        int nbatch = m.x & 255;
        dv = __int_as_float(m.y);
        u16x8 v = z[(size_t)node * 8 + c];       // self-loop term z_v
        #pragma unroll
        for (int i = 0; i < 8; ++i) s[i] = __half2float(__ushort_as_half(v[i]));
        s = gather_rows(z, csr, start, nbatch, c, s);
    }
    __syncthreads();                             // Ws fully staged
    f32x8 u = shfl_mm8(s, Ws4, c);
    if (node < n) {
        float4 b0 = ((const float4*)b)[2 * c];
        float4 b1 = ((const float4*)b)[2 * c + 1];
        f32x8 r;
        r[0] = fmaxf(fmaf(dv, u[0], b0.x), 0.f) * dv;
        r[1] = fmaxf(fmaf(dv, u[1], b0.y), 0.f) * dv;
        r[2] = fmaxf(fmaf(dv, u[2], b0.z), 0.f) * dv;
        r[3] = fmaxf(fmaf(dv, u[3], b0.w), 0.f) * dv;
        r[4] = fmaxf(fmaf(dv, u[4], b1.x), 0.f) * dv;
        r[5] = fmaxf(fmaf(dv, u[5], b1.y), 0.f) * dv;
        r[6] = fmaxf(fmaf(dv, u[6], b1.z), 0.f) * dv;
        r[7] = fmaxf(fmaf(dv, u[7], b1.w), 0.f) * dv;
        zout[(size_t)node * 8 + c] = f8_to_h8(r);    // z_{l+1}
    }
}

// ---------------------------------------------------------------------------
// Final: s = gather(z2); h = relu(dis*(s@W2)+b2); out = h @ linW + linb.
// Second mm: lane c computes output col c (all 8 lanes active).
// ---------------------------------------------------------------------------
__global__ __launch_bounds__(TPB) void layer_final(const u16x8* __restrict__ z,
                                                   const int* __restrict__ csr,
                                                   const int2* __restrict__ meta,
                                                   const float* __restrict__ b,
                                                   const float* __restrict__ W,
                                                   const float* __restrict__ Wl,
                                                   const float* __restrict__ bl,
                                                   float* __restrict__ out, int n) {
    __shared__ float Ws[64 * 64];
    __shared__ float Wls[64 * 8];
    __shared__ float bls[8];
    int t = threadIdx.x;
    float4* Ws4 = (float4*)Ws;
    const float4* W4g = (const float4*)W;
    #pragma unroll
    for (int i = 0; i < 4; ++i) Ws4[t + i * TPB] = W4g[t + i * TPB];
    if (t < 128) ((float4*)Wls)[t] = ((const float4*)Wl)[t];
    if (t < 8) bls[t] = bl[t];

    int wave = t >> 6, lane = t & 63;
    int g = lane >> 3, c = lane & 7;
    int node = blockIdx.x * 32 + wave * 8 + g;
    f32x8 s = {0.f, 0.f, 0.f, 0.f, 0.f, 0.f, 0.f, 0.f};
    float dv = 0.f;
    if (node < n) {
        int2 m = meta[node];
        int start = ((unsigned)m.x) >> 8;
        int nbatch = m.x & 255;
        dv = __int_as_float(m.y);
        u16x8 v = z[(size_t)node * 8 + c];
        #pragma unroll
        for (int i = 0; i < 8; ++i) s[i] = __half2float(__ushort_as_half(v[i]));
        s = gather_rows(z, csr, start, nbatch, c, s);
    }
    __syncthreads();                             // Ws/Wls/bls staged
    f32x8 u = shfl_mm8(s, Ws4, c);
    float4 b0 = ((const float4*)b)[2 * c];
    float4 b1 = ((const float4*)b)[2 * c + 1];
    f32x8 h;
    h[0] = fmaxf(fmaf(dv, u[0], b0.x), 0.f);
    h[1] = fmaxf(fmaf(dv, u[1], b0.y), 0.f);
    h[2] = fmaxf(fmaf(dv, u[2], b0.z), 0.f);
    h[3] = fmaxf(fmaf(dv, u[3], b0.w), 0.f);
    h[4] = fmaxf(fmaf(dv, u[4], b1.x), 0.f);
    h[5] = fmaxf(fmaf(dv, u[5], b1.y), 0.f);
    h[6] = fmaxf(fmaf(dv, u[6], b1.z), 0.f);
    h[7] = fmaxf(fmaf(dv, u[7], b1.w), 0.f);

    // second mm (64 -> 8): lane c computes output col c.
    const int base = threadIdx.x & 56;
    float acc = bls[c];
    #pragma unroll
    for (int q = 0; q < 8; ++q) {
        #pragma unroll
        for (int r = 0; r < 8; ++r) {
            float hv = __shfl(h[r], base + q);   // feature q*8+r
            acc = fmaf(hv, Wls[(q * 8 + r) * 8 + c], acc);
        }
    }
    if (node < n) out[(size_t)node * 8 + c] = acc;
}

extern "C" void kernel_launch(void* const* d_in, const int* in_sizes, int n_in,
                              void* d_out, int out_size, void* d_ws, size_t ws_size,
                              hipStream_t stream) {
    const float* x  = (const float*)d_in[0];
    const void*  ei = d_in[1];
    const float* W0 = (const float*)d_in[2];
    const float* b0 = (const float*)d_in[3];
    const float* W1 = (const float*)d_in[4];
    const float* b1 = (const float*)d_in[5];
    const float* W2 = (const float*)d_in[6];
    const float* b2 = (const float*)d_in[7];
    const float* Wl = (const float*)d_in[8];
    const float* bl = (const float*)d_in[9];

    const long long E = in_sizes[1] / 2;                 // 800000
    const int dh = in_sizes[3];                          // 64
    const int din = in_sizes[2] / dh;                    // 64
    const int N = in_sizes[0] / din;                     // 50000
    const int nb = (N + 255) >> 8;                       // 196 buckets

    // Workspace carve (256-aligned): ~39 MB total
    char* ws = (char*)d_ws;
    size_t off = 0;
    auto alloc = [&](size_t bytes) -> char* {
        char* r = ws + off;
        off += (bytes + 255) & ~(size_t)255;
        return r;
    };
    int*   gcur    = (int*)  alloc(1024);
    int2*  meta    = (int2*) alloc((size_t)N * 8);
    int*   pairs   = (int*)  alloc((size_t)nb * CAP * 4);       // 12.8 MB
    int*   csr     = (int*)  alloc((size_t)nb * CAP * 4);       // 12.8 MB
    u16x8* zbA     = (u16x8*)alloc((size_t)(N + 1) * 64 * 2);   // fp16 rows (+zero row)
    u16x8* zbB     = (u16x8*)alloc((size_t)(N + 1) * 64 * 2);

    // --- preprocessing ---
    hipMemsetAsync(gcur, 0, 256 * sizeof(int), stream);
    p3_scatter<<<SC_BLOCKS, TPB, 0, stream>>>(ei, E, gcur, pairs);
    p4_fill<<<nb, TPB, 0, stream>>>(pairs, gcur, x, meta, csr,
                                    (ushort4*)zbA, N);

    // --- 3 layers: gather -> mm -> relu ---
    const int gL = (N + 31) / 32;                        // 1563
    layer_mm<<<gL, TPB, 0, stream>>>(zbA, csr, meta, b0, W0, zbB, N);
    layer_mm<<<gL, TPB, 0, stream>>>(zbB, csr, meta, b1, W1, zbA, N);
    layer_final<<<gL, TPB, 0, stream>>>(zbA, csr, meta, b2, W2, Wl, bl,
                                        (float*)d_out, N);
}